// Round 1
// baseline (683.857 us; speedup 1.0000x reference)
//
#include <hip/hip_runtime.h>
#include <hip/hip_bf16.h>
#include <stdint.h>

typedef unsigned short u16;
typedef __attribute__((ext_vector_type(8))) short bf16x8;   // 8 bf16 (4 VGPRs)
typedef __attribute__((ext_vector_type(4))) float f32x4;    // 4 fp32 acc

#define TOKENS   16384
#define HIDDEN   2048
#define QKV_OUT  3072
#define NEXP     4

#define BM 128
#define BN 128
#define BK 64
#define RT_TILES (TOKENS / BM)    // 128
#define CT_TILES (QKV_OUT / BN)   // 24

// ---------------- fp32 -> bf16 (RNE) conversion, vectorized ----------------

__device__ __forceinline__ uint32_t f2bf(float f) {
  uint32_t u = __builtin_bit_cast(uint32_t, f);
  return (u + 0x7FFFu + ((u >> 16) & 1u)) >> 16;   // round-nearest-even
}

__global__ void cvt_f32_to_bf16(const float* __restrict__ in,
                                u16* __restrict__ out, long n8) {
  long i0 = (long)blockIdx.x * blockDim.x + threadIdx.x;
  long stride = (long)gridDim.x * blockDim.x;
  for (long p = i0; p < n8; p += stride) {
    const float4* s = (const float4*)in + p * 2;
    float4 a = s[0], b = s[1];
    uint4 q;
    q.x = f2bf(a.x) | (f2bf(a.y) << 16);
    q.y = f2bf(a.z) | (f2bf(a.w) << 16);
    q.z = f2bf(b.x) | (f2bf(b.y) << 16);
    q.w = f2bf(b.z) | (f2bf(b.w) << 16);
    ((uint4*)out)[p] = q;
  }
}

// ---------------- async global -> LDS, 16B per lane ----------------

typedef const __attribute__((address_space(1))) void* gptr_t;
typedef __attribute__((address_space(3))) void* lptr_t;

__device__ __forceinline__ void gload16(const u16* g, u16* lds) {
  // LDS dest is wave-uniform base; HW scatters lane l at base + l*16.
  __builtin_amdgcn_global_load_lds((gptr_t)g, (lptr_t)lds, 16, 0, 0);
}

// ---------------- grouped bf16 GEMM: out[t,:] = x[t,:] @ W[mm[t]].T ----------------
// m97 structure: 128x128 tile, BK=64, 4 waves (2x2), 64x64 per wave,
// 16x16x32 bf16 MFMA, single LDS buffer, 2 barriers per K-step.

__global__ void moe_qkv_gemm(const u16* __restrict__ Xb,   // [TOKENS][HIDDEN] bf16
                             const u16* __restrict__ Wb,   // [NEXP][QKV_OUT][HIDDEN] bf16
                             const int* __restrict__ mm,   // [TOKENS] sorted expert ids
                             float* __restrict__ out) {    // [TOKENS][QKV_OUT] fp32
  __shared__ u16 As[BM * BK];   // 16 KB, linear row-major [128][64]
  __shared__ u16 Bs[BN * BK];   // 16 KB

  // XCD-aware bijective swizzle (nwg=3072, 3072 % 8 == 0): each XCD gets a
  // contiguous chunk of rt-major tile space -> A-panel (512 KB) L2-resident.
  const int nwg = RT_TILES * CT_TILES;          // 3072
  const int cpx = nwg >> 3;                     // 384
  int bid = blockIdx.x;
  int swz = (bid & 7) * cpx + (bid >> 3);
  const int rt = swz / CT_TILES;
  const int ct = swz % CT_TILES;

  const int row0 = rt * BM;
  const int col0 = ct * BN;

  const int tid  = threadIdx.x;
  const int lane = tid & 63;
  const int wid  = tid >> 6;
  const int wr   = wid >> 1;      // wave row (0..1): 64-row slab
  const int wc   = wid & 1;       // wave col (0..1): 64-col slab

  // experts present in this row-tile (mm is sorted -> contiguous range)
  const int e_lo = mm[row0];
  const int e_hi = mm[row0 + BM - 1];

  f32x4 acc[4][4];
#pragma unroll
  for (int m = 0; m < 4; ++m)
#pragma unroll
    for (int n = 0; n < 4; ++n) acc[m][n] = (f32x4){0.f, 0.f, 0.f, 0.f};

  // staging coords: issue i covers rows [i*32, i*32+32); this thread owns
  // row i*32 + srow, 16B chunk at bf16 col scol. Matches gload_lds's
  // linear base + lane*16 layout exactly.
  const int srow = wid * 8 + (lane >> 3);
  const int scol = (lane & 7) * 8;

  auto compute_tile = [&]() {
#pragma unroll
    for (int kk = 0; kk < BK; kk += 32) {
      bf16x8 af[4], bfr[4];
#pragma unroll
      for (int m = 0; m < 4; ++m)
        af[m] = *(const bf16x8*)&As[(wr * 64 + m * 16 + (lane & 15)) * BK + kk + (lane >> 4) * 8];
#pragma unroll
      for (int n = 0; n < 4; ++n)
        bfr[n] = *(const bf16x8*)&Bs[(wc * 64 + n * 16 + (lane & 15)) * BK + kk + (lane >> 4) * 8];
#pragma unroll
      for (int m = 0; m < 4; ++m)
#pragma unroll
        for (int n = 0; n < 4; ++n)
          acc[m][n] = __builtin_amdgcn_mfma_f32_16x16x32_bf16(af[m], bfr[n], acc[m][n], 0, 0, 0);
    }
  };

  if (e_lo == e_hi) {
    // ---- fast path: whole tile belongs to one expert ----
    const u16* We   = Wb + (size_t)e_lo * QKV_OUT * HIDDEN;
    const u16* Arow = Xb + (size_t)row0 * HIDDEN;
    const u16* Brow = We + (size_t)col0 * HIDDEN;
    for (int kt = 0; kt < HIDDEN; kt += BK) {
#pragma unroll
      for (int i = 0; i < 4; ++i) {
        gload16(Arow + (size_t)(i * 32 + srow) * HIDDEN + kt + scol, &As[i * 2048 + wid * 512]);
        gload16(Brow + (size_t)(i * 32 + srow) * HIDDEN + kt + scol, &Bs[i * 2048 + wid * 512]);
      }
      __syncthreads();   // compiler drains vmcnt before s_barrier
      compute_tile();
      __syncthreads();
    }
  } else {
    // ---- boundary tile (<=3 of 128): masked-sum over experts, like reference ----
    for (int e = e_lo; e <= e_hi; ++e) {
      const u16* We   = Wb + (size_t)e * QKV_OUT * HIDDEN;
      const u16* Brow = We + (size_t)col0 * HIDDEN;
      bool keep[4];
#pragma unroll
      for (int i = 0; i < 4; ++i) keep[i] = (mm[row0 + i * 32 + srow] == e);
      for (int kt = 0; kt < HIDDEN; kt += BK) {
#pragma unroll
        for (int i = 0; i < 4; ++i) {
          uint4 v = make_uint4(0u, 0u, 0u, 0u);
          if (keep[i])
            v = *(const uint4*)&Xb[(size_t)(row0 + i * 32 + srow) * HIDDEN + kt + scol];
          *(uint4*)&As[(i * 32 + srow) * BK + scol] = v;   // ds_write_b128, conflict-free
          gload16(Brow + (size_t)(i * 32 + srow) * HIDDEN + kt + scol, &Bs[i * 2048 + wid * 512]);
        }
        __syncthreads();
        compute_tile();
        __syncthreads();
      }
    }
  }

  // ---- epilogue: C/D layout col=lane&15, row=(lane>>4)*4+j (m89/m91 verified) ----
#pragma unroll
  for (int m = 0; m < 4; ++m)
#pragma unroll
    for (int n = 0; n < 4; ++n) {
      f32x4 c = acc[m][n];
      int r0 = row0 + wr * 64 + m * 16 + (lane >> 4) * 4;
      int cc = col0 + wc * 64 + n * 16 + (lane & 15);
#pragma unroll
      for (int j = 0; j < 4; ++j)
        out[(size_t)(r0 + j) * QKV_OUT + cc] = c[j];
    }
}

// ---------------- launch ----------------

extern "C" void kernel_launch(void* const* d_in, const int* in_sizes, int n_in,
                              void* d_out, int out_size, void* d_ws, size_t ws_size,
                              hipStream_t stream) {
  const float* x  = (const float*)d_in[0];
  const float* W  = (const float*)d_in[1];
  const int*   mm = (const int*)d_in[2];
  float* out = (float*)d_out;

  // workspace: bf16 copies of x and W (67.1 MB + 50.3 MB = 117.4 MB)
  u16* Xb = (u16*)d_ws;
  u16* Wb = Xb + (size_t)TOKENS * HIDDEN;

  const long nx8 = (long)TOKENS * HIDDEN / 8;          // 4,194,304
  const long nw8 = (long)NEXP * QKV_OUT * HIDDEN / 8;  // 3,145,728
  cvt_f32_to_bf16<<<2048, 256, 0, stream>>>(x, Xb, nx8);
  cvt_f32_to_bf16<<<2048, 256, 0, stream>>>(W, Wb, nw8);

  moe_qkv_gemm<<<RT_TILES * CT_TILES, 256, 0, stream>>>(Xb, Wb, mm, out);
}

// Round 3
// 652.735 us; speedup vs baseline: 1.0477x; 1.0477x over previous
//
#include <hip/hip_runtime.h>
#include <hip/hip_bf16.h>
#include <stdint.h>

typedef unsigned short u16;
typedef __attribute__((ext_vector_type(8))) short bf16x8;   // 8 bf16 (4 VGPRs)
typedef __attribute__((ext_vector_type(4))) float f32x4;    // 4 fp32 acc

#define TOKENS   16384
#define HIDDEN   2048
#define QKV_OUT  3072
#define NEXP     4

#define BM 128
#define BN 128
#define BK 64
#define RT_TILES (TOKENS / BM)    // 128
#define CT_TILES (QKV_OUT / BN)   // 24

// ---------------- fp32 -> bf16 (RNE) conversion, single-pass fused ----------------

__device__ __forceinline__ uint32_t f2bf(float f) {
  uint32_t u = __builtin_bit_cast(uint32_t, f);
  return (u + 0x7FFFu + ((u >> 16) & 1u)) >> 16;   // round-nearest-even
}

#define NX8 ((long)TOKENS * HIDDEN / 8)            // 4,194,304
#define NW8 ((long)NEXP * QKV_OUT * HIDDEN / 8)    // 3,145,728

__global__ void cvt_all(const float* __restrict__ x, const float* __restrict__ W,
                        u16* __restrict__ Xb, u16* __restrict__ Wb) {
  long gid = (long)blockIdx.x * blockDim.x + threadIdx.x;   // one 16B-out chunk/thread
  const float* src; u16* dst; long p;
  if (gid < NX8) { src = x;  dst = Xb; p = gid; }
  else           { src = W;  dst = Wb; p = gid - NX8; }
  const float4* s = (const float4*)src + p * 2;
  float4 a = s[0], b = s[1];
  uint4 q;
  q.x = f2bf(a.x) | (f2bf(a.y) << 16);
  q.y = f2bf(a.z) | (f2bf(a.w) << 16);
  q.z = f2bf(b.x) | (f2bf(b.y) << 16);
  q.w = f2bf(b.z) | (f2bf(b.w) << 16);
  ((uint4*)dst)[p] = q;
}

// ---------------- async global -> LDS, 16B per lane ----------------

typedef const __attribute__((address_space(1))) void* gptr_t;
typedef __attribute__((address_space(3))) void* lptr_t;

__device__ __forceinline__ void gload16(const u16* g, u16* lds) {
  // LDS dest is wave-uniform base; HW scatters lane l at base + l*16 (linear).
  __builtin_amdgcn_global_load_lds((gptr_t)g, (lptr_t)lds, 16, 0, 0);
}

// LDS tile geometry: [128 rows][8 chunks of 16B].  Physical chunk of logical
// chunk c in row r is c ^ (r & 7)  (st-style XOR swizzle).  gload_lds writes
// LINEARLY (phys chunk = lane&7), so the SOURCE global column is pre-swizzled
// with the same XOR (rule #21: both-sides-or-neither).
__device__ __forceinline__ int lds_u16(int row, int chunk) {
  return row * BK + ((chunk ^ (row & 7)) << 3);
}

// ---------------- grouped bf16 GEMM: out[t,:] = x[t,:] @ W[mm[t]].T ----------------
// m97 structure: 128x128 tile, BK=64, 4 waves (2x2), 64x64 per wave,
// 16x16x32 bf16 MFMA, single LDS buffer, 2 barriers per K-step.

__global__ void moe_qkv_gemm(const u16* __restrict__ Xb,   // [TOKENS][HIDDEN] bf16
                             const u16* __restrict__ Wb,   // [NEXP][QKV_OUT][HIDDEN] bf16
                             const int* __restrict__ mm,   // [TOKENS] sorted expert ids
                             float* __restrict__ out) {    // [TOKENS][QKV_OUT] fp32
  __shared__ u16 As[BM * BK];   // 16 KB
  __shared__ u16 Bs[BN * BK];   // 16 KB

  // XCD-aware bijective swizzle (nwg=3072 % 8 == 0): 16 consecutive row-tiles
  // per XCD -> A panel (512 KB bf16) L2-resident across its 24 column tiles.
  const int nwg = RT_TILES * CT_TILES;          // 3072
  const int cpx = nwg >> 3;                     // 384
  int bid = blockIdx.x;
  int swz = (bid & 7) * cpx + (bid >> 3);
  const int rt = swz / CT_TILES;
  const int ct = swz % CT_TILES;

  const int row0 = rt * BM;
  const int col0 = ct * BN;

  const int tid  = threadIdx.x;
  const int lane = tid & 63;
  const int wid  = tid >> 6;
  const int wr   = wid >> 1;      // wave row (0..1): 64-row slab
  const int wc   = wid & 1;       // wave col (0..1): 64-col slab

  // experts in this row-tile (mm sorted -> contiguous range)
  const int e_lo = mm[row0];
  const int e_hi = mm[row0 + BM - 1];

  f32x4 acc[4][4];
#pragma unroll
  for (int m = 0; m < 4; ++m)
#pragma unroll
    for (int n = 0; n < 4; ++n) acc[m][n] = (f32x4){0.f, 0.f, 0.f, 0.f};

  // staging coords: issue i covers rows [i*32, i*32+32); this thread's lane
  // lands at LDS row srow_i = i*32 + wid*8 + (lane>>3), phys chunk lane&7.
  // The logical chunk that belongs there is (lane&7) ^ (srow & 7); srow&7
  // == (lane>>3)&7 since wid*8 is 0 mod 8.
  const int srow  = wid * 8 + (lane >> 3);
  const int schk  = (lane & 7) ^ ((lane >> 3) & 7);   // pre-swizzled source chunk
  const int scol  = schk << 3;                        // bf16 col of 16B chunk

  auto compute_tile = [&]() {
#pragma unroll
    for (int kk = 0; kk < 2; ++kk) {                  // two K=32 halves
      const int chunk = kk * 4 + (lane >> 4);         // logical 16B chunk 0..7
      bf16x8 af[4], bfr[4];
#pragma unroll
      for (int m = 0; m < 4; ++m)
        af[m] = *(const bf16x8*)&As[lds_u16(wr * 64 + m * 16 + (lane & 15), chunk)];
#pragma unroll
      for (int n = 0; n < 4; ++n)
        bfr[n] = *(const bf16x8*)&Bs[lds_u16(wc * 64 + n * 16 + (lane & 15), chunk)];
#pragma unroll
      for (int m = 0; m < 4; ++m)
#pragma unroll
        for (int n = 0; n < 4; ++n)
          acc[m][n] = __builtin_amdgcn_mfma_f32_16x16x32_bf16(af[m], bfr[n], acc[m][n], 0, 0, 0);
    }
  };

  if (e_lo == e_hi) {
    // ---- fast path: whole row-tile belongs to one expert (>=125/128 tiles) ----
    const u16* We   = Wb + (size_t)e_lo * QKV_OUT * HIDDEN;
    const u16* Arow = Xb + (size_t)row0 * HIDDEN;
    const u16* Brow = We + (size_t)col0 * HIDDEN;
    for (int kt = 0; kt < HIDDEN; kt += BK) {
#pragma unroll
      for (int i = 0; i < 4; ++i) {
        gload16(Arow + (size_t)(i * 32 + srow) * HIDDEN + kt + scol, &As[i * 2048 + wid * 512]);
        gload16(Brow + (size_t)(i * 32 + srow) * HIDDEN + kt + scol, &Bs[i * 2048 + wid * 512]);
      }
      __syncthreads();   // compiler drains vmcnt before s_barrier
      compute_tile();
      __syncthreads();
    }
  } else {
    // ---- boundary tile (<=3 of 128): masked-sum over experts (ref semantics) ----
    for (int e = e_lo; e <= e_hi; ++e) {
      const u16* We   = Wb + (size_t)e * QKV_OUT * HIDDEN;
      const u16* Brow = We + (size_t)col0 * HIDDEN;
      bool keep[4];
#pragma unroll
      for (int i = 0; i < 4; ++i) keep[i] = (mm[row0 + i * 32 + srow] == e);
      for (int kt = 0; kt < HIDDEN; kt += BK) {
#pragma unroll
        for (int i = 0; i < 4; ++i) {
          uint4 v = make_uint4(0u, 0u, 0u, 0u);
          if (keep[i])
            v = *(const uint4*)&Xb[(size_t)(row0 + i * 32 + srow) * HIDDEN + kt + scol];
          // same mapping as gload path: phys chunk = lane&7 at row i*32+srow,
          // holding logical chunk schk -> identical layout to fast path.
          *(uint4*)&As[(i * 32 + srow) * BK + ((lane & 7) << 3)] = v;
          gload16(Brow + (size_t)(i * 32 + srow) * HIDDEN + kt + scol, &Bs[i * 2048 + wid * 512]);
        }
        __syncthreads();
        compute_tile();
        __syncthreads();
      }
    }
  }

  // ---- epilogue: C/D layout col=lane&15, row=(lane>>4)*4+j (m89/m91 verified) ----
#pragma unroll
  for (int m = 0; m < 4; ++m)
#pragma unroll
    for (int n = 0; n < 4; ++n) {
      f32x4 c = acc[m][n];
      int r0 = row0 + wr * 64 + m * 16 + (lane >> 4) * 4;
      int cc = col0 + wc * 64 + n * 16 + (lane & 15);
#pragma unroll
      for (int j = 0; j < 4; ++j)
        out[(size_t)(r0 + j) * QKV_OUT + cc] = c[j];
    }
}

// ---------------- launch ----------------

extern "C" void kernel_launch(void* const* d_in, const int* in_sizes, int n_in,
                              void* d_out, int out_size, void* d_ws, size_t ws_size,
                              hipStream_t stream) {
  const float* x  = (const float*)d_in[0];
  const float* W  = (const float*)d_in[1];
  const int*   mm = (const int*)d_in[2];
  float* out = (float*)d_out;

  // workspace: bf16 copies of x and W (67.1 MB + 50.3 MB = 117.4 MB)
  u16* Xb = (u16*)d_ws;
  u16* Wb = Xb + (size_t)TOKENS * HIDDEN;

  const long ntot8 = NX8 + NW8;                       // 7,340,032 chunks
  cvt_all<<<(int)(ntot8 / 256), 256, 0, stream>>>(x, W, Xb, Wb);

  moe_qkv_gemm<<<RT_TILES * CT_TILES, 256, 0, stream>>>(Xb, Wb, mm, out);
}

// Round 5
// 652.148 us; speedup vs baseline: 1.0486x; 1.0009x over previous
//
#include <hip/hip_runtime.h>
#include <hip/hip_bf16.h>
#include <stdint.h>

typedef unsigned short u16;
typedef __attribute__((ext_vector_type(8))) short bf16x8;   // 8 bf16 (4 VGPRs)
typedef __attribute__((ext_vector_type(4))) float f32x4;    // 4 fp32 acc

#define TOKENS   16384
#define HIDDEN   2048
#define QKV_OUT  3072
#define NEXP     4

#define BM 256
#define BN 256
#define BK 64
#define NT       (HIDDEN / BK)         // 32 K-tiles
#define RT_TILES (TOKENS / BM)         // 64
#define CT_TILES (QKV_OUT / BN)        // 12
#define NBLK     (RT_TILES * CT_TILES) // 768
#define TSZ      (256 * 64)            // u16 per 32KB operand buffer

// ---------------- fp32 -> bf16 (RNE) conversion, single-pass fused ----------------

__device__ __forceinline__ uint32_t f2bf(float f) {
  uint32_t u = __builtin_bit_cast(uint32_t, f);
  return (u + 0x7FFFu + ((u >> 16) & 1u)) >> 16;   // round-nearest-even
}

#define NX8 ((long)TOKENS * HIDDEN / 8)            // 4,194,304
#define NW8 ((long)NEXP * QKV_OUT * HIDDEN / 8)    // 3,145,728

__global__ void cvt_all(const float* __restrict__ x, const float* __restrict__ W,
                        u16* __restrict__ Xb, u16* __restrict__ Wb) {
  long gid = (long)blockIdx.x * blockDim.x + threadIdx.x;   // one 16B-out chunk/thread
  const float* src; u16* dst; long p;
  if (gid < NX8) { src = x;  dst = Xb; p = gid; }
  else           { src = W;  dst = Wb; p = gid - NX8; }
  const float4* s = (const float4*)src + p * 2;
  float4 a = s[0], b = s[1];
  uint4 q;
  q.x = f2bf(a.x) | (f2bf(a.y) << 16);
  q.y = f2bf(a.z) | (f2bf(a.w) << 16);
  q.z = f2bf(b.x) | (f2bf(b.y) << 16);
  q.w = f2bf(b.z) | (f2bf(b.w) << 16);
  ((uint4*)dst)[p] = q;
}

// ---------------- async global -> LDS, 16B per lane ----------------

typedef const __attribute__((address_space(1))) void* gptr_t;
typedef __attribute__((address_space(3))) void* lptr_t;

// HW-verified (R3: SQ_LDS_BANK_CONFLICT == 0): within a 256x64 u16 buffer,
// phys 16B-chunk of logical chunk c in row r is c ^ (r&7). gload_lds writes
// linearly, so the global SOURCE column is pre-swizzled (rule #21).
__device__ __forceinline__ int lds_off(int row, int chunk) {
  return row * BK + ((chunk ^ (row & 7)) << 3);
}

// stage one 64-row quarter q of an operand tile (K-tile kt) into Lbuf.
// 512 threads x 16B = 8KB = 64 rows. One gload per wave (vmcnt +1/wave).
__device__ __forceinline__ void stage_q(const u16* gsrc, u16* Lbuf, int kt,
                                        int q, int tid) {
  const int r    = tid >> 3;                    // 0..63 row within quarter
  const int schk = (tid & 7) ^ (r & 7);         // pre-swizzled source chunk
  const u16* g = gsrc + (size_t)(q * 64 + r) * HIDDEN + kt * BK + schk * 8;
  u16* dst = Lbuf + (q * 64 + (tid >> 6) * 8) * BK;   // wave-uniform base
  __builtin_amdgcn_global_load_lds((gptr_t)g, (lptr_t)dst, 16, 0, 0);
}

// ---------------- grouped bf16 GEMM, 256x256 8-phase (T1+T2+T3+T4+T5) ----------------
// vmcnt ledger (per wave; every wave issues every stage_q exactly once):
//   steady state: at each VM2 (phases p3/p7) exactly 10 loads were in flight;
//   vmcnt(2) retires the 8 oldest == the COMPLETE tile read next phase; the 2
//   left outstanding are always the current phase's own stages, first read
//   4+ phases (>=4 barriers) later.  Final iteration is PEELED: p3 drains
//   vmcnt(0) (no new stages), p4-p7 compute only.  (Unpeeled version had the
//   last-iteration race: tile31 B Q2/Q3 could still be in flight at p4.)

__global__ void __launch_bounds__(512, 2)
moe_qkv_gemm(const u16* __restrict__ Xb,   // [TOKENS][HIDDEN] bf16
             const u16* __restrict__ Wb,   // [NEXP][QKV_OUT][HIDDEN] bf16
             const int* __restrict__ mm,   // [TOKENS] sorted expert ids
             float* __restrict__ out) {    // [TOKENS][QKV_OUT] fp32
  extern __shared__ u16 Lds[];   // [buf0.A][buf0.B][buf1.A][buf1.B], 4 x 32KB

  // XCD-aware bijective swizzle (768 % 8 == 0), rt-major chunks per XCD.
  const int cpx = NBLK >> 3;                    // 96
  int bid = blockIdx.x;
  int swz = (bid & 7) * cpx + (bid >> 3);
  const int rt = swz / CT_TILES;
  const int ct = swz % CT_TILES;
  const int row0 = rt * BM;
  const int col0 = ct * BN;

  const int tid  = threadIdx.x;
  const int lane = tid & 63;
  const int wid  = tid >> 6;
  const int wr   = wid >> 2;      // 0..1 : 128-row slab
  const int wc   = wid & 3;       // 0..3 : 64-col slab

  const int e_lo = mm[row0];
  const int e_hi = mm[row0 + BM - 1];

  f32x4 acc[8][4];
#pragma unroll
  for (int m = 0; m < 8; ++m)
#pragma unroll
    for (int n = 0; n < 4; ++n) acc[m][n] = (f32x4){0.f, 0.f, 0.f, 0.f};

  if (e_lo == e_hi) {
    // ================= fast path: uniform expert (>=61/64 row-tiles) ==========
    const u16* Asrc = Xb + (size_t)row0 * HIDDEN;
    const u16* Bsrc = Wb + (size_t)e_lo * QKV_OUT * HIDDEN + (size_t)col0 * HIDDEN;

#define LA_OF(t) (Lds + (((t) & 1) * 2) * TSZ)
#define LB_OF(t) (Lds + (((t) & 1) * 2 + 1) * TSZ)

    // ---- prologue: tile0 fully + tile1 AQ0,AQ2; leave tile1's 2 outstanding
    {
#pragma unroll
      for (int q = 0; q < 4; ++q) stage_q(Asrc, LA_OF(0), 0, q, tid);
#pragma unroll
      for (int q = 0; q < 4; ++q) stage_q(Bsrc, LB_OF(0), 0, q, tid);
      stage_q(Asrc, LA_OF(1), 1, 0, tid);
      stage_q(Asrc, LA_OF(1), 1, 2, tid);
      asm volatile("s_waitcnt vmcnt(2)" ::: "memory");
      __builtin_amdgcn_s_barrier();
      __builtin_amdgcn_sched_barrier(0);
    }

    // One phase: {8 ds_read ; stage 2 quarters ; [vmcnt] ; barrier ;
    //             lgkmcnt(0)+sched_barrier ; setprio(1) 16xMFMA setprio(0) ; barrier}
#define PHASE(BUF, KS, MH, STAGE_CODE, VMW)                                        \
    {                                                                              \
      const u16* LA = Lds + ((BUF) * 2) * TSZ;                                     \
      const u16* LB = Lds + ((BUF) * 2 + 1) * TSZ;                                 \
      const int chunk = (KS) * 4 + (lane >> 4);                                    \
      bf16x8 af[4], bfr[4];                                                        \
      _Pragma("unroll")                                                            \
      for (int m = 0; m < 4; ++m)                                                  \
        af[m] = *(const bf16x8*)&LA[lds_off(wr * 128 + ((MH) * 4 + m) * 16 + (lane & 15), chunk)]; \
      _Pragma("unroll")                                                            \
      for (int n = 0; n < 4; ++n)                                                  \
        bfr[n] = *(const bf16x8*)&LB[lds_off(wc * 64 + n * 16 + (lane & 15), chunk)]; \
      STAGE_CODE;                                                                  \
      VMW;                                                                         \
      __builtin_amdgcn_s_barrier();                                                \
      asm volatile("s_waitcnt lgkmcnt(0)" ::: "memory");                           \
      __builtin_amdgcn_sched_barrier(0);                                           \
      __builtin_amdgcn_s_setprio(1);                                               \
      _Pragma("unroll")                                                            \
      for (int m = 0; m < 4; ++m)                                                  \
        _Pragma("unroll")                                                          \
        for (int n = 0; n < 4; ++n)                                                \
          acc[(MH) * 4 + m][n] = __builtin_amdgcn_mfma_f32_16x16x32_bf16(          \
              af[m], bfr[n], acc[(MH) * 4 + m][n], 0, 0, 0);                       \
      __builtin_amdgcn_s_setprio(0);                                               \
      __builtin_amdgcn_s_barrier();                                                \
      __builtin_amdgcn_sched_barrier(0);                                           \
    }

#define VM2 asm volatile("s_waitcnt vmcnt(2)" ::: "memory")
#define VM0 asm volatile("s_waitcnt vmcnt(0)" ::: "memory")

    // ---- main loop: 15 iterations x 2 K-tiles, unconditional stages.
    // Quarter liveness: buf.A Q0/Q2 read at MH=0 phases, Q1/Q3 at MH=1,
    // buf.B all quarters every phase of its tile -> restage only after the
    // tile's last phase (barrier-separated).
    for (int it = 0; it < 15; ++it) {
      const int t1 = 2 * it + 1, t2 = 2 * it + 2, t3 = 2 * it + 3;
      // tile 2it in buf0
      PHASE(0, 0, 0, { stage_q(Asrc, LA_OF(t1), t1, 1, tid);
                       stage_q(Asrc, LA_OF(t1), t1, 3, tid); }, );
      PHASE(0, 0, 1, { stage_q(Bsrc, LB_OF(t1), t1, 0, tid);
                       stage_q(Bsrc, LB_OF(t1), t1, 1, tid); }, );
      PHASE(0, 1, 0, { stage_q(Bsrc, LB_OF(t1), t1, 2, tid);
                       stage_q(Bsrc, LB_OF(t1), t1, 3, tid); }, );
      PHASE(0, 1, 1, { stage_q(Asrc, LA_OF(t2), t2, 0, tid);
                       stage_q(Asrc, LA_OF(t2), t2, 2, tid); }, VM2);
      // tile 2it+1 in buf1
      PHASE(1, 0, 0, { stage_q(Asrc, LA_OF(t2), t2, 1, tid);
                       stage_q(Asrc, LA_OF(t2), t2, 3, tid); }, );
      PHASE(1, 0, 1, { stage_q(Bsrc, LB_OF(t2), t2, 0, tid);
                       stage_q(Bsrc, LB_OF(t2), t2, 1, tid); }, );
      PHASE(1, 1, 0, { stage_q(Bsrc, LB_OF(t2), t2, 2, tid);
                       stage_q(Bsrc, LB_OF(t2), t2, 3, tid); }, );
      PHASE(1, 1, 1, { stage_q(Asrc, LA_OF(t3), t3, 0, tid);
                       stage_q(Asrc, LA_OF(t3), t3, 2, tid); }, VM2);
    }
    // ---- peeled final iteration: tiles 30 (buf0) / 31 (buf1) ----
    PHASE(0, 0, 0, { stage_q(Asrc, LA_OF(31), 31, 1, tid);
                     stage_q(Asrc, LA_OF(31), 31, 3, tid); }, );
    PHASE(0, 0, 1, { stage_q(Bsrc, LB_OF(31), 31, 0, tid);
                     stage_q(Bsrc, LB_OF(31), 31, 1, tid); }, );
    PHASE(0, 1, 0, { stage_q(Bsrc, LB_OF(31), 31, 2, tid);
                     stage_q(Bsrc, LB_OF(31), 31, 3, tid); }, );
    PHASE(0, 1, 1, { }, VM0);   // drain: ALL of tile31 landed before buf1 reads
    PHASE(1, 0, 0, { }, );
    PHASE(1, 0, 1, { }, );
    PHASE(1, 1, 0, { }, );
    PHASE(1, 1, 1, { }, );
#undef PHASE
#undef VM2
#undef VM0

  } else {
    // ================= boundary tiles (<=3/64): masked-sum over experts =======
    u16* LA = Lds;
    u16* LB = Lds + TSZ;
    const int r    = tid >> 3;
    const int schk = (tid & 7) ^ (r & 7);
    for (int e = e_lo; e <= e_hi; ++e) {
      const u16* Bsrc = Wb + (size_t)e * QKV_OUT * HIDDEN + (size_t)col0 * HIDDEN;
      bool keep[4];
#pragma unroll
      for (int q = 0; q < 4; ++q) keep[q] = (mm[row0 + q * 64 + r] == e);
      for (int kt = 0; kt < NT; ++kt) {
#pragma unroll
        for (int q = 0; q < 4; ++q) stage_q(Bsrc, LB, kt, q, tid);
#pragma unroll
        for (int q = 0; q < 4; ++q) {
          uint4 v = make_uint4(0u, 0u, 0u, 0u);
          if (keep[q])
            v = *(const uint4*)&Xb[(size_t)(row0 + q * 64 + r) * HIDDEN + kt * BK + schk * 8];
          *(uint4*)&LA[(q * 64 + r) * BK + (tid & 7) * 8] = v;   // phys-linear write
        }
        __syncthreads();   // drains vmcnt+lgkmcnt (slow path: correctness first)
#pragma unroll
        for (int ks = 0; ks < 2; ++ks) {
          const int chunk = ks * 4 + (lane >> 4);
          bf16x8 af[8], bfr[4];
#pragma unroll
          for (int m = 0; m < 8; ++m)
            af[m] = *(const bf16x8*)&LA[lds_off(wr * 128 + m * 16 + (lane & 15), chunk)];
#pragma unroll
          for (int n = 0; n < 4; ++n)
            bfr[n] = *(const bf16x8*)&LB[lds_off(wc * 64 + n * 16 + (lane & 15), chunk)];
#pragma unroll
          for (int m = 0; m < 8; ++m)
#pragma unroll
            for (int n = 0; n < 4; ++n)
              acc[m][n] = __builtin_amdgcn_mfma_f32_16x16x32_bf16(af[m], bfr[n], acc[m][n], 0, 0, 0);
        }
        __syncthreads();
      }
    }
  }

  // ---- epilogue: C/D layout col=lane&15, row=(lane>>4)*4+j (R3-verified) ----
#pragma unroll
  for (int m = 0; m < 8; ++m)
#pragma unroll
    for (int n = 0; n < 4; ++n) {
      f32x4 c = acc[m][n];
      int r0 = row0 + wr * 128 + m * 16 + (lane >> 4) * 4;
      int cc = col0 + wc * 64 + n * 16 + (lane & 15);
#pragma unroll
      for (int j = 0; j < 4; ++j)
        out[(size_t)(r0 + j) * QKV_OUT + cc] = c[j];
    }
}

// ---------------- launch ----------------

extern "C" void kernel_launch(void* const* d_in, const int* in_sizes, int n_in,
                              void* d_out, int out_size, void* d_ws, size_t ws_size,
                              hipStream_t stream) {
  const float* x  = (const float*)d_in[0];
  const float* W  = (const float*)d_in[1];
  const int*   mm = (const int*)d_in[2];
  float* out = (float*)d_out;

  u16* Xb = (u16*)d_ws;                              // 67.1 MB bf16 x
  u16* Wb = Xb + (size_t)TOKENS * HIDDEN;            // 50.3 MB bf16 W

  const long ntot8 = NX8 + NW8;                      // 7,340,032 chunks
  cvt_all<<<(int)(ntot8 / 256), 256, 0, stream>>>(x, W, Xb, Wb);

  hipFuncSetAttribute((const void*)moe_qkv_gemm,
                      hipFuncAttributeMaxDynamicSharedMemorySize, 131072);
  moe_qkv_gemm<<<NBLK, 512, 131072, stream>>>(Xb, Wb, mm, out);
}